// Round 7
// baseline (354.370 us; speedup 1.0000x reference)
//
#include <hip/hip_runtime.h>
#include <math.h>

#define IN_DIM 256
#define OUT_DIM 64
#define NEG_SLOPE 0.2f
#define EPS_GAT 1e-9f

typedef __attribute__((ext_vector_type(8))) short short8v;
typedef __attribute__((ext_vector_type(4))) float float4v;

// Bucketing: bucket(d) = d >> 8  (G = 256 dsts per bucket).
// NB = ceil(N/256) <= 1024 assumed (N = 100K -> NB = 391).
// pairs[] entry: (dlow << 24) | src   (src < 2^24 assumed)

// ---------------------------------------------------------------------------
// split fp32 -> bf16 hi (RNE) + bf16 lo (trunc of remainder).
// x ~= hi + lo with ~2^-17 relative error; lo*lo term dropped in MFMA.
// ---------------------------------------------------------------------------
struct bfrag { short8v hi, lo; };

__device__ __forceinline__ bfrag split8(float4 a, float4 b) {
    float f[8] = {a.x, a.y, a.z, a.w, b.x, b.y, b.z, b.w};
    bfrag r;
    #pragma unroll
    for (int j = 0; j < 8; ++j) {
        unsigned u = __float_as_uint(f[j]);
        unsigned t = (u + 0x7FFFu + ((u >> 16) & 1u)) >> 16;   // RNE bf16
        r.hi[j] = (short)t;
        float rem = f[j] - __uint_as_float(t << 16);
        r.lo[j] = (short)(__float_as_uint(rem) >> 16);          // trunc bf16
    }
    return r;
}

// ---------------------------------------------------------------------------
// K1 (MFMA): h = X @ W^T via split-bf16 (3-term emulation), fused a_s/a_d.
// One wave per 16 nodes; no LDS, no barriers. mfma_f32_16x16x32_bf16:
//   A-frag: lane l holds X[m0+(l&15)][k0+(l>>4)*8+j]   (row-major contig)
//   B-frag: lane l holds B[k][n] = W[n][k] -> W[nf*16+(l&15)][k0+(l>>4)*8+j]
//   C/D   : col = l&15, row = (l>>4)*4 + reg            (m89 mapping)
// W (64KB) is L2-resident; re-read per wave.
// ---------------------------------------------------------------------------
__global__ __launch_bounds__(256) void gat_k1_mfma(
    const float* __restrict__ X, const float* __restrict__ W,
    const float* __restrict__ attn, float* __restrict__ h,
    float* __restrict__ a_s, float* __restrict__ a_d, int N)
{
    const int lane = threadIdx.x & 63;
    const int gw = blockIdx.x * 4 + (threadIdx.x >> 6);
    const int m0 = gw * 16;
    if (m0 >= N) return;

    const int row = lane & 15;       // A-row / B-col / D-col
    const int q   = lane >> 4;       // k-quarter (0..3)
    const int kb  = q * 2;           // float4 offset within 32-k slab

    const float4* X4 = (const float4*)X;
    const float4* W4 = (const float4*)W;

    const int rx = min(m0 + row, N - 1);   // clamped A row

    // attn slices for fused epilogue: dim = nf*16 + col(=row)
    float at_s[4], at_d[4];
    #pragma unroll
    for (int nf = 0; nf < 4; ++nf) {
        at_s[nf] = attn[nf * 16 + row];
        at_d[nf] = attn[OUT_DIM + nf * 16 + row];
    }

    float4v acc[4];
    #pragma unroll
    for (int nf = 0; nf < 4; ++nf) acc[nf] = (float4v){0.f, 0.f, 0.f, 0.f};

    #pragma unroll
    for (int k0 = 0; k0 < IN_DIM; k0 += 32) {
        const int c4 = (k0 >> 2) + kb;
        const float4* xp = X4 + (size_t)rx * 64 + c4;
        bfrag af = split8(xp[0], xp[1]);
        #pragma unroll
        for (int nf = 0; nf < 4; ++nf) {
            const float4* wp = W4 + (size_t)(nf * 16 + row) * 64 + c4;
            bfrag bf = split8(wp[0], wp[1]);
            acc[nf] = __builtin_amdgcn_mfma_f32_16x16x32_bf16(af.hi, bf.hi, acc[nf], 0, 0, 0);
            acc[nf] = __builtin_amdgcn_mfma_f32_16x16x32_bf16(af.hi, bf.lo, acc[nf], 0, 0, 0);
            acc[nf] = __builtin_amdgcn_mfma_f32_16x16x32_bf16(af.lo, bf.hi, acc[nf], 0, 0, 0);
        }
    }

    // epilogue: lane holds D[row=(q*4+r)][col=row_var] per nf
    #pragma unroll
    for (int r = 0; r < 4; ++r) {
        const int node = m0 + q * 4 + r;
        float vs = 0.f, vd = 0.f;
        #pragma unroll
        for (int nf = 0; nf < 4; ++nf) {
            const float v = acc[nf][r];
            if (node < N) h[(size_t)node * OUT_DIM + nf * 16 + row] = v;
            vs += v * at_s[nf];
            vd += v * at_d[nf];
        }
        vs += __shfl_xor(vs, 1); vs += __shfl_xor(vs, 2);
        vs += __shfl_xor(vs, 4); vs += __shfl_xor(vs, 8);
        vd += __shfl_xor(vd, 1); vd += __shfl_xor(vd, 2);
        vd += __shfl_xor(vd, 4); vd += __shfl_xor(vd, 8);
        if (row == 0 && node < N) { a_s[node] = vs; a_d[node] = vd; }
    }
}

// ---------------------------------------------------------------------------
// P1a: bucket histogram (LDS-reduced)
// ---------------------------------------------------------------------------
__global__ __launch_bounds__(256) void gat_p1a_bhist(
    const int* __restrict__ dst, int* __restrict__ bucketCnt, int E, int NB)
{
    __shared__ int cnt[1024];
    const int tid = threadIdx.x;
    for (int i = tid; i < NB; i += 256) cnt[i] = 0;
    __syncthreads();
    const int gtid = blockIdx.x * 256 + tid;
    const int gsz  = gridDim.x * 256;
    const int E4 = E >> 2;
    const int4* d4 = (const int4*)dst;
    for (int i = gtid; i < E4; i += gsz) {
        int4 v = d4[i];
        atomicAdd(&cnt[v.x >> 8], 1);
        atomicAdd(&cnt[v.y >> 8], 1);
        atomicAdd(&cnt[v.z >> 8], 1);
        atomicAdd(&cnt[v.w >> 8], 1);
    }
    for (int i = (E4 << 2) + gtid; i < E; i += gsz)
        atomicAdd(&cnt[dst[i] >> 8], 1);
    __syncthreads();
    for (int i = tid; i < NB; i += 256)
        if (cnt[i]) atomicAdd(&bucketCnt[i], cnt[i]);
}

// ---------------------------------------------------------------------------
// P1b: exclusive scan of bucketCnt (NB <= 1024) -> bucketBase, bucketCursor.
// ---------------------------------------------------------------------------
__global__ __launch_bounds__(1024) void gat_p1b_bscan(
    const int* __restrict__ bucketCnt, int* __restrict__ bucketBase,
    int* __restrict__ bucketCursor, int NB)
{
    __shared__ int wsum[16];
    const int t = threadIdx.x;
    const int lane = t & 63;
    const int wave = t >> 6;
    const int v = (t < NB) ? bucketCnt[t] : 0;
    int incl = v;
    #pragma unroll
    for (int off = 1; off < 64; off <<= 1) {
        int x = __shfl_up(incl, off);
        if (lane >= off) incl += x;
    }
    if (lane == 63) wsum[wave] = incl;
    __syncthreads();
    if (wave == 0) {
        int wv = (lane < 16) ? wsum[lane] : 0;
        int wincl = wv;
        #pragma unroll
        for (int off = 1; off < 16; off <<= 1) {
            int x = __shfl_up(wincl, off);
            if (lane >= off) wincl += x;
        }
        if (lane < 16) wsum[lane] = wincl - wv;
    }
    __syncthreads();
    if (t < NB) {
        const int excl = wsum[wave] + (incl - v);
        bucketBase[t] = excl;
        bucketCursor[t] = excl;
    }
}

// ---------------------------------------------------------------------------
// P1c: partition edges into bucket-grouped pairs[] via per-(block,bucket)
// contiguous run reservation.
// ---------------------------------------------------------------------------
__global__ __launch_bounds__(256) void gat_p1c_partition(
    const int* __restrict__ src, const int* __restrict__ dst,
    int* __restrict__ bucketCursor, unsigned* __restrict__ pairs, int E)
{
    __shared__ int cnt[1024];
    __shared__ int run[1024];
    const int tid = threadIdx.x;
    const int chunk = (E + gridDim.x - 1) / gridDim.x;
    const int beg = blockIdx.x * chunk;
    const int end = min(E, beg + chunk);

    for (int i = tid; i < 1024; i += 256) cnt[i] = 0;
    __syncthreads();
    for (int i = beg + tid; i < end; i += 256)
        atomicAdd(&cnt[dst[i] >> 8], 1);
    __syncthreads();
    for (int i = tid; i < 1024; i += 256) {
        const int c = cnt[i];
        run[i] = c ? atomicAdd(&bucketCursor[i], c) : 0;
    }
    __syncthreads();
    for (int i = beg + tid; i < end; i += 256) {
        const int d = dst[i];
        const int pos = atomicAdd(&run[d >> 8], 1);
        pairs[pos] = ((unsigned)(d & 255) << 24) | (unsigned)src[i];
    }
}

// ---------------------------------------------------------------------------
// P2: one block per bucket -> per-dst CSR (offsets/counts/sorted_src).
// ---------------------------------------------------------------------------
__global__ __launch_bounds__(256) void gat_p2_csr(
    const unsigned* __restrict__ pairs, const int* __restrict__ bucketBase,
    const int* __restrict__ bucketCnt, int* __restrict__ offsets,
    int* __restrict__ counts, int* __restrict__ sorted_src, int N)
{
    __shared__ int cnt[256];
    __shared__ int offAbs[256];
    __shared__ int wsum[4];
    const int b = blockIdx.x;
    const int t = threadIdx.x;
    const int base = bucketBase[b];
    const int ecnt = bucketCnt[b];

    cnt[t] = 0;
    __syncthreads();
    for (int i = base + t; i < base + ecnt; i += 256)
        atomicAdd(&cnt[pairs[i] >> 24], 1);
    __syncthreads();

    const int lane = t & 63;
    const int wave = t >> 6;
    const int v = cnt[t];
    int incl = v;
    #pragma unroll
    for (int off = 1; off < 64; off <<= 1) {
        int x = __shfl_up(incl, off);
        if (lane >= off) incl += x;
    }
    if (lane == 63) wsum[wave] = incl;
    __syncthreads();
    int wpre = 0;
    for (int w = 0; w < wave; ++w) wpre += wsum[w];
    const int abs0 = base + wpre + (incl - v);
    offAbs[t] = abs0;
    const int d = b * 256 + t;
    if (d < N) { offsets[d] = abs0; counts[d] = v; }
    __syncthreads();

    for (int i = base + t; i < base + ecnt; i += 256) {
        const unsigned pv = pairs[i];
        const int pos = atomicAdd(&offAbs[pv >> 24], 1);
        sorted_src[pos] = (int)(pv & 0xFFFFFFu);
    }
}

// ---------------------------------------------------------------------------
// K5: one wave per dst; e recomputed from a_s[s]+a_d[d]. Slot decomposition:
// 64 lanes = 4 edges x 16 dim-quarters. base = offsets[d] (segment base).
// ---------------------------------------------------------------------------
__global__ __launch_bounds__(256) void gat_k5_aggregate(
    const float* __restrict__ h, const int* __restrict__ sorted_src,
    const int* __restrict__ offsets, const int* __restrict__ counts,
    const float* __restrict__ a_s, const float* __restrict__ a_d,
    const float* __restrict__ bias, float* __restrict__ out, int N)
{
    const int wave = threadIdx.x >> 6, lane = threadIdx.x & 63;
    const int d = blockIdx.x * 4 + wave;
    if (d >= N) return;
    const int deg  = counts[d];
    const int base = offsets[d];
    const float ad = a_d[d];
    const int slot = lane >> 4, q = lane & 15;
    const float4* h4 = (const float4*)h;

    float4 acc = {0.f, 0.f, 0.f, 0.f};

    if (deg <= 64) {
        int s = 0; float e = -INFINITY;
        if (lane < deg) {
            s = sorted_src[base + lane];
            e = a_s[s] + ad;
            e = (e >= 0.f) ? e : NEG_SLOPE * e;
        }
        float m = e;
        #pragma unroll
        for (int off = 32; off; off >>= 1) m = fmaxf(m, __shfl_xor(m, off));
        float p = (lane < deg) ? __expf(e - m) : 0.f;
        float sum = p;
        #pragma unroll
        for (int off = 32; off; off >>= 1) sum += __shfl_xor(sum, off);
        const float w = p / (sum + EPS_GAT);
        for (int t0 = 0; t0 < deg; t0 += 4) {
            const float wg = __shfl(w, t0 + slot);
            const int  sid = __shfl(s, t0 + slot);
            float4 hv = h4[(size_t)sid * 16 + q];
            acc.x += wg * hv.x; acc.y += wg * hv.y;
            acc.z += wg * hv.z; acc.w += wg * hv.w;
        }
    } else {
        float m = -INFINITY;
        for (int j = lane; j < deg; j += 64) {
            float e = a_s[sorted_src[base + j]] + ad;
            e = (e >= 0.f) ? e : NEG_SLOPE * e;
            m = fmaxf(m, e);
        }
        #pragma unroll
        for (int off = 32; off; off >>= 1) m = fmaxf(m, __shfl_xor(m, off));
        float sum = 0.f;
        for (int j = lane; j < deg; j += 64) {
            float e = a_s[sorted_src[base + j]] + ad;
            e = (e >= 0.f) ? e : NEG_SLOPE * e;
            sum += __expf(e - m);
        }
        #pragma unroll
        for (int off = 32; off; off >>= 1) sum += __shfl_xor(sum, off);
        const float inv = 1.f / (sum + EPS_GAT);
        for (int j0 = 0; j0 < deg; j0 += 64) {
            int s = 0; float w = 0.f;
            if (j0 + lane < deg) {
                s = sorted_src[base + j0 + lane];
                float e = a_s[s] + ad;
                e = (e >= 0.f) ? e : NEG_SLOPE * e;
                w = __expf(e - m) * inv;
            }
            const int cnt = min(64, deg - j0);
            for (int t0 = 0; t0 < cnt; t0 += 4) {
                const float wg = __shfl(w, t0 + slot);
                const int  sid = __shfl(s, t0 + slot);
                float4 hv = h4[(size_t)sid * 16 + q];
                acc.x += wg * hv.x; acc.y += wg * hv.y;
                acc.z += wg * hv.z; acc.w += wg * hv.w;
            }
        }
    }

    acc.x += __shfl_xor(acc.x, 16); acc.x += __shfl_xor(acc.x, 32);
    acc.y += __shfl_xor(acc.y, 16); acc.y += __shfl_xor(acc.y, 32);
    acc.z += __shfl_xor(acc.z, 16); acc.z += __shfl_xor(acc.z, 32);
    acc.w += __shfl_xor(acc.w, 16); acc.w += __shfl_xor(acc.w, 32);

    if (slot == 0) {
        const float4* b4 = (const float4*)bias;
        float4 bv = b4[q];
        float4 o;
        o.x = acc.x + bv.x; o.y = acc.y + bv.y;
        o.z = acc.z + bv.z; o.w = acc.w + bv.w;
        ((float4*)out)[(size_t)d * 16 + q] = o;
    }
}

// ---------------------------------------------------------------------------
extern "C" void kernel_launch(void* const* d_in, const int* in_sizes, int n_in,
                              void* d_out, int out_size, void* d_ws, size_t ws_size,
                              hipStream_t stream)
{
    const float* X    = (const float*)d_in[0];
    const int*   EI   = (const int*)d_in[1];
    const float* W    = (const float*)d_in[2];
    const float* attn = (const float*)d_in[3];
    const float* bias = (const float*)d_in[4];
    float* out = (float*)d_out;

    const int N = in_sizes[0] / IN_DIM;
    const int E = in_sizes[1] / 2;
    const int* src = EI;
    const int* dst = EI + E;
    const int NB = (N + 255) >> 8;   // <= 1024 assumed (N=100K -> 391)

    // workspace layout (16B-aligned blocks)
    char* ws = (char*)d_ws;
    float* h      = (float*)ws; ws += (size_t)N * OUT_DIM * sizeof(float);
    float* a_s    = (float*)ws; ws += (size_t)N * sizeof(float);
    float* a_d    = (float*)ws; ws += (size_t)N * sizeof(float);
    int*   counts = (int*)ws;   ws += (size_t)N * sizeof(int);
    int*   offsets= (int*)ws;   ws += (size_t)N * sizeof(int);
    int*   bucketCnt    = (int*)ws; ws += 1024 * sizeof(int);   // zeroed
    int*   bucketBase   = (int*)ws; ws += 1024 * sizeof(int);
    int*   bucketCursor = (int*)ws; ws += 1024 * sizeof(int);
    unsigned* pairs     = (unsigned*)ws; ws += (size_t)E * sizeof(unsigned);
    int*   sorted_src   = (int*)ws;      ws += (size_t)E * sizeof(int);

    hipMemsetAsync(bucketCnt, 0, 1024 * sizeof(int), stream);

    const int nwaves = (N + 15) / 16;
    gat_k1_mfma<<<(nwaves + 3) / 4, 256, 0, stream>>>(X, W, attn, h, a_s, a_d, N);
    gat_p1a_bhist<<<256, 256, 0, stream>>>(dst, bucketCnt, E, NB);
    gat_p1b_bscan<<<1, 1024, 0, stream>>>(bucketCnt, bucketBase, bucketCursor, NB);
    gat_p1c_partition<<<128, 256, 0, stream>>>(src, dst, bucketCursor, pairs, E);
    gat_p2_csr<<<NB, 256, 0, stream>>>(pairs, bucketBase, bucketCnt, offsets,
                                       counts, sorted_src, N);
    gat_k5_aggregate<<<(N + 3) / 4, 256, 0, stream>>>(h, sorted_src, offsets, counts,
                                                      a_s, a_d, bias, out, N);
}